// Round 5
// baseline (294.823 us; speedup 1.0000x reference)
//
#include <hip/hip_runtime.h>

#define N_NODES 50000
#define N_EDGES 800000
#define D 128
#define BN_EPS 1e-5f

#define NBUCK 391        // ceil(N_NODES / 128)
#define BSHIFT 7         // 128 nodes per bucket
#define S1_BLOCKS 256
#define EPB 3125         // edges per histogram/scatter block (256*3125 == 800000)
#define CVT_BLOCKS 6250  // N_NODES*D/4 / 256
#define PACK_BLOCKS 384  // 3*32768 / 256
#define NREP 16          // stats replica count (atomic-contention spread)
#define NSLICE 8         // src-slice bins for L2-locality sort (50000>>13 -> 0..6)
#define SSHIFT 13        // 8192 nodes/slice = 2 MB of bf16 rows (fits per-XCD L2)
#define BN_BLOCKS 512

typedef __attribute__((ext_vector_type(8))) short bf16x8;
typedef __attribute__((ext_vector_type(4))) float f32x4;
typedef __attribute__((ext_vector_type(2))) float f32x2;

// fp32 -> bf16 (RNE)
__device__ inline unsigned short f2bf(float f) {
    unsigned int u = __float_as_uint(f);
    u = (u + 0x7FFF + ((u >> 16) & 1)) >> 16;
    return (unsigned short)u;
}

__device__ inline float bf2f(unsigned short b) {
    return __uint_as_float(((unsigned)b) << 16);
}

// packed-pair accumulate: 2 extracts + 1 (pk_)add per bf16 pair
__device__ __forceinline__ void acc_plain(f32x2* a, uint4 v) {
    unsigned w[4] = {v.x, v.y, v.z, v.w};
#pragma unroll
    for (int p = 0; p < 4; p++) {
        f32x2 f;
        f.x = __uint_as_float(w[p] << 16);          // even col
        f.y = __uint_as_float(w[p] & 0xffff0000u);  // odd col
        a[p] += f;
    }
}

// ---------------- fused prep: convert_x | edge histogram | pack_w (+zero) ----------

__global__ void fused_prep(const float* __restrict__ x, unsigned short* __restrict__ x16,
                           const int* __restrict__ dst, int* __restrict__ hist,
                           const float* __restrict__ Ws0, const float* __restrict__ Wn0,
                           const float* __restrict__ Ws1, const float* __restrict__ Wn1,
                           const float* __restrict__ Ws2, const float* __restrict__ Wn2,
                           unsigned short* __restrict__ Wf, float* __restrict__ statsg) {
    __shared__ int lh[NBUCK];
    const int bid = blockIdx.x, t = threadIdx.x;

    if (bid < CVT_BLOCKS) {
        int idx = bid * 256 + t;
        float4 v = ((const float4*)x)[idx];
        ushort4 o;
        o.x = f2bf(v.x); o.y = f2bf(v.y); o.z = f2bf(v.z); o.w = f2bf(v.w);
        ((ushort4*)x16)[idx] = o;
    } else if (bid < CVT_BLOCKS + S1_BLOCKS) {
        int blk = bid - CVT_BLOCKS;
        for (int i = t; i < NBUCK; i += 256) lh[i] = 0;
        __syncthreads();
        int e0 = blk * EPB;
        for (int i = 0; i < 13; i++) {
            int k = t + i * 256;
            if (k < EPB) atomicAdd(&lh[dst[e0 + k] >> BSHIFT], 1);
        }
        __syncthreads();
        for (int i = t; i < NBUCK; i += 256) hist[blk * NBUCK + i] = lh[i];
    } else {
        if (bid == CVT_BLOCKS + S1_BLOCKS) {   // zero BN stats: 2 layers x NREP x 256
            for (int i = t; i < 2 * NREP * 256; i += 256) statsg[i] = 0.f;
        }
        // pack weights into MFMA B-fragment order:
        // Wf[layer][kt(8)][nt(8)][lane(64)][j(8)], lane l holds
        // B[kt*32 + 8*(l>>4) + j][nt*16 + (l&15)].
        int idx = (bid - (CVT_BLOCKS + S1_BLOCKS)) * 256 + t;
        if (idx < 3 * 32768) {
            int layer = idx >> 15;
            int rem = idx & 32767;
            int kt = rem >> 12;
            int nt = (rem >> 9) & 7;
            int lane = (rem >> 3) & 63;
            int j = rem & 7;
            int k = kt * 32 + (lane >> 4) * 8 + j;
            int n = nt * 16 + (lane & 15);
            const float* Wsrc;
            if (layer == 0) Wsrc = (k < 128) ? Ws0 : Wn0;
            else if (layer == 1) Wsrc = (k < 128) ? Ws1 : Wn1;
            else Wsrc = (k < 128) ? Ws2 : Wn2;
            Wf[idx] = f2bf(Wsrc[(k & 127) * D + n]);
        }
    }
}

// ---------------- S2a: per-bucket exclusive prefix over blocks ----------------
// Separate kernels on purpose: round-7's grid-barrier merge (sort_all) ran 97 us
// vs ~35 us for this pipeline — barrier serialization at 1 block/CU.

__global__ void s2a(int* __restrict__ hist, int* __restrict__ bucketTotal) {
    __shared__ int s[S1_BLOCKS];
    int b = blockIdx.x, t = threadIdx.x;
    int v = hist[t * NBUCK + b];
    s[t] = v;
    __syncthreads();
    for (int off = 1; off < S1_BLOCKS; off <<= 1) {
        int x = (t >= off) ? s[t - off] : 0;
        __syncthreads();
        s[t] += x;
        __syncthreads();
    }
    hist[t * NBUCK + b] = s[t] - v;
    if (t == S1_BLOCKS - 1) bucketTotal[b] = s[t];
}

// ---------------- S3: scatter packed records, bucket-grouped ----------------
// Each block redundantly scans the 391 bucket totals in LDS (cheap, parallel —
// removes the s2b dispatch); block 0 publishes bucketStart for s4_build.

__global__ void s3_scatter(const int* __restrict__ src, const int* __restrict__ dst,
                           const int* __restrict__ hist, const int* __restrict__ bucketTotal,
                           int* __restrict__ bucketStart, unsigned int* __restrict__ rec) {
    __shared__ int sc[512];
    __shared__ int base[NBUCK];
    int blk = blockIdx.x, t = threadIdx.x;
    int i1 = t + 256;
    int v0 = (t < NBUCK) ? bucketTotal[t] : 0;
    int v1 = (i1 < NBUCK) ? bucketTotal[i1] : 0;
    sc[t] = v0; sc[i1] = v1;
    __syncthreads();
    for (int off = 1; off < 512; off <<= 1) {
        int x0 = (t >= off) ? sc[t - off] : 0;
        int x1 = (i1 >= off) ? sc[i1 - off] : 0;
        __syncthreads();
        sc[t] += x0; sc[i1] += x1;
        __syncthreads();
    }
    if (t < NBUCK)  base[t]  = (sc[t] - v0)  + hist[blk * NBUCK + t];
    if (i1 < NBUCK) base[i1] = (sc[i1] - v1) + hist[blk * NBUCK + i1];
    if (blk == 0) {
        if (t < NBUCK)  bucketStart[t]  = sc[t] - v0;
        if (i1 < NBUCK) bucketStart[i1] = sc[i1] - v1;
        if (t == 0) bucketStart[NBUCK] = N_EDGES;
    }
    __syncthreads();
    int e0 = blk * EPB;
    for (int i = 0; i < 13; i++) {
        int k = t + i * 256;
        if (k < EPB) {
            int e = e0 + k;
            int d = dst[e];
            int p = atomicAdd(&base[d >> BSHIFT], 1);
            rec[p] = ((unsigned)(d & 127) << 16) | (unsigned)src[e];
        }
    }
}

// ---------------- S4: per-bucket counting sort -> CSR + degrees ----------------
// Round-11: sort key extended to (dst&127, src>>13) so each neighbor list is
// grouped by 2 MB source slice. All aggregate16 blocks then sweep slices in
// loose lockstep -> gather working set becomes L2-resident per XCD.

__global__ void s4_build(const unsigned int* __restrict__ rec, const int* __restrict__ bucketStart,
                         unsigned short* __restrict__ csr, int* __restrict__ degi,
                         int* __restrict__ offsets, float* __restrict__ inv_deg) {
    __shared__ int cnt[128 * NSLICE];
    __shared__ int exc[128 * NSLICE];
    __shared__ int lcur[128 * NSLICE];
    __shared__ int ls[256];
    int b = blockIdx.x, t = threadIdx.x;
    int start = bucketStart[b], end = bucketStart[b + 1];

    for (int i = t; i < 128 * NSLICE; i += 256) cnt[i] = 0;
    __syncthreads();
    for (int e = start + t; e < end; e += 256) {
        unsigned r = rec[e];
        int key = ((r >> 16) << 3) | ((r & 0xFFFFu) >> SSHIFT);
        atomicAdd(&cnt[key], 1);
    }
    __syncthreads();

    // 1024-bin exclusive scan: 4 bins/thread, block scan over partials
    int c0 = cnt[4 * t], c1 = cnt[4 * t + 1], c2 = cnt[4 * t + 2], c3 = cnt[4 * t + 3];
    int sum4 = c0 + c1 + c2 + c3;
    ls[t] = sum4;
    __syncthreads();
    for (int off = 1; off < 256; off <<= 1) {
        int x = (t >= off) ? ls[t - off] : 0;
        __syncthreads();
        ls[t] += x;
        __syncthreads();
    }
    int base = ls[t] - sum4;
    exc[4 * t]     = base;
    exc[4 * t + 1] = base + c0;
    exc[4 * t + 2] = base + c0 + c1;
    exc[4 * t + 3] = base + c0 + c1 + c2;
    lcur[4 * t]     = start + base;
    lcur[4 * t + 1] = start + base + c0;
    lcur[4 * t + 2] = start + base + c0 + c1;
    lcur[4 * t + 3] = start + base + c0 + c1 + c2;
    __syncthreads();

    if (t < 128) {
        int node = (b << BSHIFT) + t;
        int e0 = exc[8 * t];
        int e1 = (t == 127) ? (end - start) : exc[8 * t + 8];
        int v = e1 - e0;
        if (node < N_NODES) {
            degi[node] = v;
            offsets[node] = start + e0;
            inv_deg[node] = 1.0f / (float)max(v, 1);
        }
    }
    __syncthreads();
    for (int e = start + t; e < end; e += 256) {
        unsigned r = rec[e];
        int key = ((r >> 16) << 3) | ((r & 0xFFFFu) >> SSHIFT);
        int p = atomicAdd(&lcur[key], 1);
        csr[p] = (unsigned short)(r & 0xFFFFu);
    }
}

// ---------------- BN+ReLU applied once per node (round-11) ----------------
// Replaces the per-edge BN in aggregate16 (16x amplified VALU + per-thread
// stats refold = ~400 MB of redundant L2 loads) and the self-fragment BN in
// sage_gemm. In-place on the bf16 activation buffer.

__global__ void bn_relu_apply(unsigned short* __restrict__ h,
                              const float* __restrict__ stats,
                              const float* __restrict__ gamma, const float* __restrict__ beta) {
    __shared__ float sc[128], sh[128];
    int t = threadIdx.x;
    if (t < 128) {
        const float invN = 1.0f / (float)N_NODES;
        float s = 0.f, q = 0.f;
#pragma unroll
        for (int r = 0; r < NREP; r++) {
            s += stats[r * 256 + t];
            q += stats[r * 256 + 128 + t];
        }
        float m = s * invN;
        float var = q * invN - m * m;
        float scv = rsqrtf(var + BN_EPS) * gamma[t];
        sc[t] = scv;
        sh[t] = beta[t] - m * scv;
    }
    __syncthreads();
    const int total = N_NODES * D / 8;  // 800000 uint4
    for (int idx = blockIdx.x * 256 + t; idx < total; idx += BN_BLOCKS * 256) {
        uint4 v = ((const uint4*)h)[idx];
        int col0 = (idx & 15) * 8;
        unsigned w[4] = {v.x, v.y, v.z, v.w};
        unsigned ow[4];
#pragma unroll
        for (int p = 0; p < 4; p++) {
            float lo = __uint_as_float(w[p] << 16);
            float hi = __uint_as_float(w[p] & 0xffff0000u);
            float rlo = fmaxf(lo * sc[col0 + 2 * p]     + sh[col0 + 2 * p],     0.f);
            float rhi = fmaxf(hi * sc[col0 + 2 * p + 1] + sh[col0 + 2 * p + 1], 0.f);
            ow[p] = ((unsigned)f2bf(rhi) << 16) | f2bf(rlo);
        }
        uint4 o;
        o.x = ow[0]; o.y = ow[1]; o.z = ow[2]; o.w = ow[3];
        ((uint4*)h)[idx] = o;
    }
}

// ---------------- mean aggregation: 1 node/wave, 4 parallel edge streams ---------
// Round-14 restructure. Round-4 falsified the divergence theory (degsort perm
// gained ~0): aggregate is gather-LATENCY-bound, not VALU-bound. So: raise MLP.
// Each wave owns ONE node; its 4 16-lane groups process interleaved edge
// streams (k = grp, grp+4, ...) each 3-deep pipelined -> ~12 loads in flight
// per wave (vs 4 before), same VALU work, zero cross-node divergence. Final
// shfl_xor(16/32) merges the 4 partial sums. Stride-4 interleave preserves the
// slice-sort L2 locality (concurrent gathers span ~12 adjacent list entries).

#define GATHER(k) (*(const uint4*)(hb + ((size_t)csr[beg + (k)] << 7)))

__global__ void aggregate16(const unsigned short* __restrict__ h16,
                            const unsigned short* __restrict__ csr, const int* __restrict__ offsets,
                            const int* __restrict__ degi, const float* __restrict__ inv_deg,
                            unsigned short* __restrict__ mean16) {
    int t = threadIdx.x;
    int node = blockIdx.x * 4 + (t >> 6);   // grid*4 == N_NODES exactly
    int lane = t & 63;
    int grp = lane >> 4;                    // edge-stream 0..3
    int c = lane & 15;                      // column group (8 cols each)
    const unsigned short* hb = h16 + c * 8;
    int beg = offsets[node], n = degi[node];
    f32x2 a[4];
#pragma unroll
    for (int j = 0; j < 4; j++) a[j] = (f32x2)(0.f);

    int rem = n - grp;                      // this stream: edges grp, grp+4, ...
    if (rem > 0) {
        uint4 v0, v1, v2;
        v0 = GATHER(grp);
        if (rem > 4) v1 = GATHER(grp + 4);
        if (rem > 8) v2 = GATHER(grp + 8);
        for (int k = grp + 12; k < n; k += 4) {
            uint4 w = GATHER(k);
            acc_plain(a, v0);
            v0 = v1; v1 = v2; v2 = w;
        }
        acc_plain(a, v0);
        if (rem > 4) acc_plain(a, v1);
        if (rem > 8) acc_plain(a, v2);
    }

    // merge the 4 stream-partials (lanes c, c+16, c+32, c+48 hold same cols)
#pragma unroll
    for (int j = 0; j < 4; j++) {
        a[j].x += __shfl_xor(a[j].x, 16);
        a[j].y += __shfl_xor(a[j].y, 16);
        a[j].x += __shfl_xor(a[j].x, 32);
        a[j].y += __shfl_xor(a[j].y, 32);
    }

    if (grp == 0) {
        float w = inv_deg[node];
        uint4 o;
        o.x = ((unsigned)f2bf(a[0].y * w) << 16) | f2bf(a[0].x * w);
        o.y = ((unsigned)f2bf(a[1].y * w) << 16) | f2bf(a[1].x * w);
        o.z = ((unsigned)f2bf(a[2].y * w) << 16) | f2bf(a[2].x * w);
        o.w = ((unsigned)f2bf(a[3].y * w) << 16) | f2bf(a[3].x * w);
        *(uint4*)(mean16 + (size_t)node * D + c * 8) = o;
    }
}

// ---------------- MFMA SAGE GEMM + fused BN col-stats ----------------
// Round-10 restructure: Wf staged in LDS 32KB at a time; B-frags via
// ds_read_b128; all 8 A-frags register-prefetched. Inputs are post-BN
// (round-11) so no self-fragment BN here. Stats scattered across NREP
// replica slots.
// C/D layout (m89-verified): col = lane&15, row = (lane>>4)*4 + reg.

__global__ __launch_bounds__(256, 4) void sage_gemm(
    const unsigned short* __restrict__ h16, const unsigned short* __restrict__ mean16,
    const unsigned short* __restrict__ Wf, const float* __restrict__ bias,
    unsigned short* __restrict__ out16, float* __restrict__ outf,
    float* __restrict__ statsOut) {
    __shared__ unsigned short sWf[16384];   // 32 KB: one K-half (4 kt x 8 nt x 64 x 8)
    __shared__ float sstat[256];
    const int t = threadIdx.x;
    const int lane = t & 63;
    const int m = lane & 15;
    const int quad = lane >> 4;
    const int wrow0 = blockIdx.x * 64 + (t >> 6) * 16;

    int arow = wrow0 + m;
    if (arow >= N_NODES) arow = N_NODES - 1;

    // prefetch all 8 A-fragments (4 self + 4 mean) into registers
    bf16x8 afr[8];
#pragma unroll
    for (int kt = 0; kt < 4; kt++)
        afr[kt] = *(const bf16x8*)(h16 + (size_t)arow * D + kt * 32 + quad * 8);
#pragma unroll
    for (int kt = 0; kt < 4; kt++)
        afr[4 + kt] = *(const bf16x8*)(mean16 + (size_t)arow * D + kt * 32 + quad * 8);

    // stage first weight half (kt 0-3)
    const uint4* W4 = (const uint4*)Wf;
    uint4* S4 = (uint4*)sWf;
#pragma unroll
    for (int i = 0; i < 8; i++) S4[i * 256 + t] = W4[i * 256 + t];
    if (statsOut) sstat[t] = 0.f;
    __syncthreads();

    f32x4 acc[8];
#pragma unroll
    for (int i = 0; i < 8; i++) acc[i] = (f32x4)(0.f);

#pragma unroll
    for (int kt = 0; kt < 4; kt++) {
#pragma unroll
        for (int nt = 0; nt < 8; nt++) {
            bf16x8 bf = *(const bf16x8*)(sWf + ((kt * 8 + nt) * 64 + lane) * 8);
            acc[nt] = __builtin_amdgcn_mfma_f32_16x16x32_bf16(afr[kt], bf, acc[nt], 0, 0, 0);
        }
    }

    __syncthreads();   // all waves done with half 1 before overwrite
#pragma unroll
    for (int i = 0; i < 8; i++) S4[i * 256 + t] = W4[2048 + i * 256 + t];
    __syncthreads();

#pragma unroll
    for (int kt = 4; kt < 8; kt++) {
#pragma unroll
        for (int nt = 0; nt < 8; nt++) {
            bf16x8 bf = *(const bf16x8*)(sWf + (((kt - 4) * 8 + nt) * 64 + lane) * 8);
            acc[nt] = __builtin_amdgcn_mfma_f32_16x16x32_bf16(afr[kt], bf, acc[nt], 0, 0, 0);
        }
    }

    const bool do16 = (out16 != nullptr);
#pragma unroll
    for (int nt = 0; nt < 8; nt++) {
        int cidx = nt * 16 + m;
        float bv = bias[cidx];
        float s = 0.f, q = 0.f;
#pragma unroll
        for (int reg = 0; reg < 4; reg++) {
            int r = wrow0 + quad * 4 + reg;
            float v = acc[nt][reg] + bv;
            if (r < N_NODES) {
                if (do16) out16[(size_t)r * D + cidx] = f2bf(v);
                else      outf[(size_t)r * D + cidx] = v;
                s += v; q += v * v;
            }
        }
        if (statsOut) {
            s += __shfl_xor(s, 16); s += __shfl_xor(s, 32);
            q += __shfl_xor(q, 16); q += __shfl_xor(q, 32);
            if (quad == 0) {
                atomicAdd(&sstat[cidx], s);
                atomicAdd(&sstat[128 + cidx], q);
            }
        }
    }
    if (statsOut) {
        __syncthreads();
        atomicAdd(&statsOut[(blockIdx.x & (NREP - 1)) * 256 + t], sstat[t]);
    }
}

// ---------------- launch ----------------

extern "C" void kernel_launch(void* const* d_in, const int* in_sizes, int n_in,
                              void* d_out, int out_size, void* d_ws, size_t ws_size,
                              hipStream_t stream) {
    const float* x   = (const float*)d_in[0];
    const int* src   = (const int*)d_in[1];
    const int* dst   = (const int*)d_in[2];
    const float* Ws0 = (const float*)d_in[3];
    const float* Wn0 = (const float*)d_in[4];
    const float* b0  = (const float*)d_in[5];
    const float* Ws1 = (const float*)d_in[6];
    const float* Wn1 = (const float*)d_in[7];
    const float* b1  = (const float*)d_in[8];
    const float* Ws2 = (const float*)d_in[9];
    const float* Wn2 = (const float*)d_in[10];
    const float* b2  = (const float*)d_in[11];
    const float* g0  = (const float*)d_in[12];
    const float* be0 = (const float*)d_in[13];
    const float* g1  = (const float*)d_in[14];
    const float* be1 = (const float*)d_in[15];

    char* base = (char*)d_ws;
    size_t NND = (size_t)N_NODES * D;
    unsigned short* X16    = (unsigned short*)base;                 // 12.8 MB
    unsigned short* H16    = (unsigned short*)(base + NND * 2);     // 12.8 MB
    unsigned short* mean16 = (unsigned short*)(base + 2 * NND * 2); // 12.8 MB
    char* p = base + 6 * NND;
    unsigned short* Wf = (unsigned short*)p;  p += 3 * 32768 * 2;                  // 192 KB
    int* hist          = (int*)p;             p += (size_t)S1_BLOCKS * NBUCK * 4;  // 400 KB
    int* bucketTotal   = (int*)p;             p += 1568;
    int* bucketStart   = (int*)p;             p += 1600;
    unsigned int* rec  = (unsigned int*)p;    p += (size_t)N_EDGES * 4;            // 3.2 MB
    unsigned short* csr = (unsigned short*)p; p += (size_t)N_EDGES * 2;            // 1.6 MB
    int* degi    = (int*)p;                   p += N_NODES * 4;
    int* offsets = (int*)p;                   p += N_NODES * 4;
    float* inv_deg = (float*)p;               p += N_NODES * 4;
    float* stats   = (float*)p;               p += 2 * NREP * 256 * 4;  // replicated
    float* stats0 = stats, *stats1 = stats + NREP * 256;

    // prep: feature convert + edge histogram + weight pack + zero stats
    fused_prep<<<CVT_BLOCKS + S1_BLOCKS + PACK_BLOCKS, 256, 0, stream>>>(
        x, X16, dst, hist, Ws0, Wn0, Ws1, Wn1, Ws2, Wn2, Wf, stats);
    // CSR build: 3 kernels (s2b folded into s3 as redundant per-block scan)
    s2a<<<NBUCK, 256, 0, stream>>>(hist, bucketTotal);
    s3_scatter<<<S1_BLOCKS, 256, 0, stream>>>(src, dst, hist, bucketTotal, bucketStart, rec);
    s4_build<<<NBUCK, 256, 0, stream>>>(rec, bucketStart, csr, degi, offsets, inv_deg);

    const int AGG_B = N_NODES / 4;           // 12500 (1 node per wave)
    const int GEMM_B = (N_NODES + 63) / 64;  // 782

    // Layer 0: X16 -> H16 raw + stats0
    aggregate16<<<AGG_B, 256, 0, stream>>>(X16, csr, offsets, degi, inv_deg, mean16);
    sage_gemm<<<GEMM_B, 256, 0, stream>>>(X16, mean16, Wf, b0, H16, nullptr, stats0);

    // Layer 1: H16 <- relu(bn0(H16)); -> X16 raw + stats1
    bn_relu_apply<<<BN_BLOCKS, 256, 0, stream>>>(H16, stats0, g0, be0);
    aggregate16<<<AGG_B, 256, 0, stream>>>(H16, csr, offsets, degi, inv_deg, mean16);
    sage_gemm<<<GEMM_B, 256, 0, stream>>>(H16, mean16, Wf + 32768, b1, X16, nullptr, stats1);

    // Layer 2: X16 <- relu(bn1(X16)); -> d_out fp32
    bn_relu_apply<<<BN_BLOCKS, 256, 0, stream>>>(X16, stats1, g1, be1);
    aggregate16<<<AGG_B, 256, 0, stream>>>(X16, csr, offsets, degi, inv_deg, mean16);
    sage_gemm<<<GEMM_B, 256, 0, stream>>>(X16, mean16, Wf + 65536, b2, nullptr,
                                          (float*)d_out, nullptr);
}

// Round 6
// 280.969 us; speedup vs baseline: 1.0493x; 1.0493x over previous
//
#include <hip/hip_runtime.h>

#define N_NODES 50000
#define N_EDGES 800000
#define D 128
#define BN_EPS 1e-5f

#define NBUCK 391        // ceil(N_NODES / 128)
#define BSHIFT 7         // 128 nodes per bucket
#define S1_BLOCKS 256
#define EPB 3125         // edges per histogram/scatter block (256*3125 == 800000)
#define CVT_BLOCKS 6250  // N_NODES*D/4 / 256
#define PACK_BLOCKS 384  // 3*32768 / 256
#define NREP 16          // stats replica count (atomic-contention spread)
#define NSLICE 8         // src-slice bins for L2-locality sort (50000>>13 -> 0..6)
#define SSHIFT 13        // 8192 nodes/slice = 2 MB of bf16 rows (fits per-XCD L2)
#define BN_BLOCKS 512

typedef __attribute__((ext_vector_type(8))) short bf16x8;
typedef __attribute__((ext_vector_type(4))) float f32x4;
typedef __attribute__((ext_vector_type(2))) float f32x2;

// fp32 -> bf16 (RNE)
__device__ inline unsigned short f2bf(float f) {
    unsigned int u = __float_as_uint(f);
    u = (u + 0x7FFF + ((u >> 16) & 1)) >> 16;
    return (unsigned short)u;
}

__device__ inline float bf2f(unsigned short b) {
    return __uint_as_float(((unsigned)b) << 16);
}

// packed-pair accumulate: 2 extracts + 1 (pk_)add per bf16 pair
__device__ __forceinline__ void acc_plain(f32x2* a, uint4 v) {
    unsigned w[4] = {v.x, v.y, v.z, v.w};
#pragma unroll
    for (int p = 0; p < 4; p++) {
        f32x2 f;
        f.x = __uint_as_float(w[p] << 16);          // even col
        f.y = __uint_as_float(w[p] & 0xffff0000u);  // odd col
        a[p] += f;
    }
}

// ---------------- fused prep: convert_x | edge histogram | pack_w (+zero) ----------

__global__ void fused_prep(const float* __restrict__ x, unsigned short* __restrict__ x16,
                           const int* __restrict__ dst, int* __restrict__ hist,
                           const float* __restrict__ Ws0, const float* __restrict__ Wn0,
                           const float* __restrict__ Ws1, const float* __restrict__ Wn1,
                           const float* __restrict__ Ws2, const float* __restrict__ Wn2,
                           unsigned short* __restrict__ Wf, float* __restrict__ statsg) {
    __shared__ int lh[NBUCK];
    const int bid = blockIdx.x, t = threadIdx.x;

    if (bid < CVT_BLOCKS) {
        int idx = bid * 256 + t;
        float4 v = ((const float4*)x)[idx];
        ushort4 o;
        o.x = f2bf(v.x); o.y = f2bf(v.y); o.z = f2bf(v.z); o.w = f2bf(v.w);
        ((ushort4*)x16)[idx] = o;
    } else if (bid < CVT_BLOCKS + S1_BLOCKS) {
        int blk = bid - CVT_BLOCKS;
        for (int i = t; i < NBUCK; i += 256) lh[i] = 0;
        __syncthreads();
        int e0 = blk * EPB;
        for (int i = 0; i < 13; i++) {
            int k = t + i * 256;
            if (k < EPB) atomicAdd(&lh[dst[e0 + k] >> BSHIFT], 1);
        }
        __syncthreads();
        for (int i = t; i < NBUCK; i += 256) hist[blk * NBUCK + i] = lh[i];
    } else {
        if (bid == CVT_BLOCKS + S1_BLOCKS) {   // zero BN stats: 2 layers x NREP x 256
            for (int i = t; i < 2 * NREP * 256; i += 256) statsg[i] = 0.f;
        }
        // pack weights into MFMA B-fragment order:
        // Wf[layer][kt(8)][nt(8)][lane(64)][j(8)], lane l holds
        // B[kt*32 + 8*(l>>4) + j][nt*16 + (l&15)].
        int idx = (bid - (CVT_BLOCKS + S1_BLOCKS)) * 256 + t;
        if (idx < 3 * 32768) {
            int layer = idx >> 15;
            int rem = idx & 32767;
            int kt = rem >> 12;
            int nt = (rem >> 9) & 7;
            int lane = (rem >> 3) & 63;
            int j = rem & 7;
            int k = kt * 32 + (lane >> 4) * 8 + j;
            int n = nt * 16 + (lane & 15);
            const float* Wsrc;
            if (layer == 0) Wsrc = (k < 128) ? Ws0 : Wn0;
            else if (layer == 1) Wsrc = (k < 128) ? Ws1 : Wn1;
            else Wsrc = (k < 128) ? Ws2 : Wn2;
            Wf[idx] = f2bf(Wsrc[(k & 127) * D + n]);
        }
    }
}

// ---------------- S2a: per-bucket exclusive prefix over blocks ----------------
// Separate kernels on purpose: round-7's grid-barrier merge (sort_all) ran 97 us
// vs ~35 us for this pipeline — barrier serialization at 1 block/CU.

__global__ void s2a(int* __restrict__ hist, int* __restrict__ bucketTotal) {
    __shared__ int s[S1_BLOCKS];
    int b = blockIdx.x, t = threadIdx.x;
    int v = hist[t * NBUCK + b];
    s[t] = v;
    __syncthreads();
    for (int off = 1; off < S1_BLOCKS; off <<= 1) {
        int x = (t >= off) ? s[t - off] : 0;
        __syncthreads();
        s[t] += x;
        __syncthreads();
    }
    hist[t * NBUCK + b] = s[t] - v;
    if (t == S1_BLOCKS - 1) bucketTotal[b] = s[t];
}

// ---------------- S3: scatter packed records, bucket-grouped ----------------
// Each block redundantly scans the 391 bucket totals in LDS (cheap, parallel —
// removes the s2b dispatch); block 0 publishes bucketStart for s4_build.

__global__ void s3_scatter(const int* __restrict__ src, const int* __restrict__ dst,
                           const int* __restrict__ hist, const int* __restrict__ bucketTotal,
                           int* __restrict__ bucketStart, unsigned int* __restrict__ rec) {
    __shared__ int sc[512];
    __shared__ int base[NBUCK];
    int blk = blockIdx.x, t = threadIdx.x;
    int i1 = t + 256;
    int v0 = (t < NBUCK) ? bucketTotal[t] : 0;
    int v1 = (i1 < NBUCK) ? bucketTotal[i1] : 0;
    sc[t] = v0; sc[i1] = v1;
    __syncthreads();
    for (int off = 1; off < 512; off <<= 1) {
        int x0 = (t >= off) ? sc[t - off] : 0;
        int x1 = (i1 >= off) ? sc[i1 - off] : 0;
        __syncthreads();
        sc[t] += x0; sc[i1] += x1;
        __syncthreads();
    }
    if (t < NBUCK)  base[t]  = (sc[t] - v0)  + hist[blk * NBUCK + t];
    if (i1 < NBUCK) base[i1] = (sc[i1] - v1) + hist[blk * NBUCK + i1];
    if (blk == 0) {
        if (t < NBUCK)  bucketStart[t]  = sc[t] - v0;
        if (i1 < NBUCK) bucketStart[i1] = sc[i1] - v1;
        if (t == 0) bucketStart[NBUCK] = N_EDGES;
    }
    __syncthreads();
    int e0 = blk * EPB;
    for (int i = 0; i < 13; i++) {
        int k = t + i * 256;
        if (k < EPB) {
            int e = e0 + k;
            int d = dst[e];
            int p = atomicAdd(&base[d >> BSHIFT], 1);
            rec[p] = ((unsigned)(d & 127) << 16) | (unsigned)src[e];
        }
    }
}

// ---------------- S4: per-bucket counting sort -> CSR + degrees ----------------
// Round-11: sort key extended to (dst&127, src>>13) so each neighbor list is
// grouped by 2 MB source slice. All aggregate16 blocks then sweep slices in
// loose lockstep -> gather working set becomes L2-resident per XCD.

__global__ void s4_build(const unsigned int* __restrict__ rec, const int* __restrict__ bucketStart,
                         unsigned short* __restrict__ csr, int* __restrict__ degi,
                         int* __restrict__ offsets, float* __restrict__ inv_deg) {
    __shared__ int cnt[128 * NSLICE];
    __shared__ int exc[128 * NSLICE];
    __shared__ int lcur[128 * NSLICE];
    __shared__ int ls[256];
    int b = blockIdx.x, t = threadIdx.x;
    int start = bucketStart[b], end = bucketStart[b + 1];

    for (int i = t; i < 128 * NSLICE; i += 256) cnt[i] = 0;
    __syncthreads();
    for (int e = start + t; e < end; e += 256) {
        unsigned r = rec[e];
        int key = ((r >> 16) << 3) | ((r & 0xFFFFu) >> SSHIFT);
        atomicAdd(&cnt[key], 1);
    }
    __syncthreads();

    // 1024-bin exclusive scan: 4 bins/thread, block scan over partials
    int c0 = cnt[4 * t], c1 = cnt[4 * t + 1], c2 = cnt[4 * t + 2], c3 = cnt[4 * t + 3];
    int sum4 = c0 + c1 + c2 + c3;
    ls[t] = sum4;
    __syncthreads();
    for (int off = 1; off < 256; off <<= 1) {
        int x = (t >= off) ? ls[t - off] : 0;
        __syncthreads();
        ls[t] += x;
        __syncthreads();
    }
    int base = ls[t] - sum4;
    exc[4 * t]     = base;
    exc[4 * t + 1] = base + c0;
    exc[4 * t + 2] = base + c0 + c1;
    exc[4 * t + 3] = base + c0 + c1 + c2;
    lcur[4 * t]     = start + base;
    lcur[4 * t + 1] = start + base + c0;
    lcur[4 * t + 2] = start + base + c0 + c1;
    lcur[4 * t + 3] = start + base + c0 + c1 + c2;
    __syncthreads();

    if (t < 128) {
        int node = (b << BSHIFT) + t;
        int e0 = exc[8 * t];
        int e1 = (t == 127) ? (end - start) : exc[8 * t + 8];
        int v = e1 - e0;
        if (node < N_NODES) {
            degi[node] = v;
            offsets[node] = start + e0;
            inv_deg[node] = 1.0f / (float)max(v, 1);
        }
    }
    __syncthreads();
    for (int e = start + t; e < end; e += 256) {
        unsigned r = rec[e];
        int key = ((r >> 16) << 3) | ((r & 0xFFFFu) >> SSHIFT);
        int p = atomicAdd(&lcur[key], 1);
        csr[p] = (unsigned short)(r & 0xFFFFu);
    }
}

// ---------------- BN+ReLU applied once per node (round-11) ----------------
// Replaces the per-edge BN in aggregate16 (16x amplified VALU + per-thread
// stats refold = ~400 MB of redundant L2 loads) and the self-fragment BN in
// sage_gemm. In-place on the bf16 activation buffer.

__global__ void bn_relu_apply(unsigned short* __restrict__ h,
                              const float* __restrict__ stats,
                              const float* __restrict__ gamma, const float* __restrict__ beta) {
    __shared__ float sc[128], sh[128];
    int t = threadIdx.x;
    if (t < 128) {
        const float invN = 1.0f / (float)N_NODES;
        float s = 0.f, q = 0.f;
#pragma unroll
        for (int r = 0; r < NREP; r++) {
            s += stats[r * 256 + t];
            q += stats[r * 256 + 128 + t];
        }
        float m = s * invN;
        float var = q * invN - m * m;
        float scv = rsqrtf(var + BN_EPS) * gamma[t];
        sc[t] = scv;
        sh[t] = beta[t] - m * scv;
    }
    __syncthreads();
    const int total = N_NODES * D / 8;  // 800000 uint4
    for (int idx = blockIdx.x * 256 + t; idx < total; idx += BN_BLOCKS * 256) {
        uint4 v = ((const uint4*)h)[idx];
        int col0 = (idx & 15) * 8;
        unsigned w[4] = {v.x, v.y, v.z, v.w};
        unsigned ow[4];
#pragma unroll
        for (int p = 0; p < 4; p++) {
            float lo = __uint_as_float(w[p] << 16);
            float hi = __uint_as_float(w[p] & 0xffff0000u);
            float rlo = fmaxf(lo * sc[col0 + 2 * p]     + sh[col0 + 2 * p],     0.f);
            float rhi = fmaxf(hi * sc[col0 + 2 * p + 1] + sh[col0 + 2 * p + 1], 0.f);
            ow[p] = ((unsigned)f2bf(rhi) << 16) | f2bf(rlo);
        }
        uint4 o;
        o.x = ow[0]; o.y = ow[1]; o.z = ow[2]; o.w = ow[3];
        ((uint4*)h)[idx] = o;
    }
}

// ---------------- mean aggregation (round-15: round-1 shape, 6-deep pipeline) -----
// Evidence ranking: round-1 shape (16 nodes/block, 4 node-streams/wave, 16
// lanes/node) = 279.6 us total; degsort perm = +8 with no divergence win
// (round-4); 1-node/wave 4-stream = -15 (round-5: it REDUCED in-flight gathers
// 16 -> 12). The aggregate is latency x outstanding-capacity bound, so this
// round keeps the round-1 shape and deepens the per-stream pipeline 4 -> 6:
// 24 gathers in flight per wave, +8 VGPR (~70 total, no occupancy cliff).

#define GATHER(k) (*(const uint4*)(hb + ((size_t)csr[beg + (k)] << 7)))

__global__ void aggregate16(const unsigned short* __restrict__ h16,
                            const unsigned short* __restrict__ csr, const int* __restrict__ offsets,
                            const int* __restrict__ degi, const float* __restrict__ inv_deg,
                            unsigned short* __restrict__ mean16) {
    int t = threadIdx.x;
    int node = blockIdx.x * 16 + (t >> 4);   // grid*16 == N_NODES exactly
    int c = t & 15;
    const unsigned short* hb = h16 + c * 8;
    int beg = offsets[node], n = degi[node];
    f32x2 a[4];
#pragma unroll
    for (int j = 0; j < 4; j++) a[j] = (f32x2)(0.f);

    int i = 0;
    if (n >= 6) {
        uint4 v0 = GATHER(0), v1 = GATHER(1), v2 = GATHER(2);
        uint4 v3 = GATHER(3), v4 = GATHER(4), v5 = GATHER(5);
        for (i = 6; i + 3 < n; i += 4) {
            uint4 w0 = GATHER(i), w1 = GATHER(i + 1), w2 = GATHER(i + 2), w3 = GATHER(i + 3);
            acc_plain(a, v0); acc_plain(a, v1); acc_plain(a, v2); acc_plain(a, v3);
            v0 = v4; v1 = v5; v2 = w0; v3 = w1; v4 = w2; v5 = w3;
        }
        acc_plain(a, v0); acc_plain(a, v1); acc_plain(a, v2);
        acc_plain(a, v3); acc_plain(a, v4); acc_plain(a, v5);
    }
    for (; i < n; i++) { uint4 v = GATHER(i); acc_plain(a, v); }

    float w = inv_deg[node];
    uint4 o;
    o.x = ((unsigned)f2bf(a[0].y * w) << 16) | f2bf(a[0].x * w);
    o.y = ((unsigned)f2bf(a[1].y * w) << 16) | f2bf(a[1].x * w);
    o.z = ((unsigned)f2bf(a[2].y * w) << 16) | f2bf(a[2].x * w);
    o.w = ((unsigned)f2bf(a[3].y * w) << 16) | f2bf(a[3].x * w);
    *(uint4*)(mean16 + (size_t)node * D + c * 8) = o;
}

// ---------------- MFMA SAGE GEMM + fused BN col-stats ----------------
// Round-10 restructure: Wf staged in LDS 32KB at a time; B-frags via
// ds_read_b128; all 8 A-frags register-prefetched. Inputs are post-BN
// (round-11) so no self-fragment BN here. Stats scattered across NREP
// replica slots.
// C/D layout (m89-verified): col = lane&15, row = (lane>>4)*4 + reg.

__global__ __launch_bounds__(256, 4) void sage_gemm(
    const unsigned short* __restrict__ h16, const unsigned short* __restrict__ mean16,
    const unsigned short* __restrict__ Wf, const float* __restrict__ bias,
    unsigned short* __restrict__ out16, float* __restrict__ outf,
    float* __restrict__ statsOut) {
    __shared__ unsigned short sWf[16384];   // 32 KB: one K-half (4 kt x 8 nt x 64 x 8)
    __shared__ float sstat[256];
    const int t = threadIdx.x;
    const int lane = t & 63;
    const int m = lane & 15;
    const int quad = lane >> 4;
    const int wrow0 = blockIdx.x * 64 + (t >> 6) * 16;

    int arow = wrow0 + m;
    if (arow >= N_NODES) arow = N_NODES - 1;

    // prefetch all 8 A-fragments (4 self + 4 mean) into registers
    bf16x8 afr[8];
#pragma unroll
    for (int kt = 0; kt < 4; kt++)
        afr[kt] = *(const bf16x8*)(h16 + (size_t)arow * D + kt * 32 + quad * 8);
#pragma unroll
    for (int kt = 0; kt < 4; kt++)
        afr[4 + kt] = *(const bf16x8*)(mean16 + (size_t)arow * D + kt * 32 + quad * 8);

    // stage first weight half (kt 0-3)
    const uint4* W4 = (const uint4*)Wf;
    uint4* S4 = (uint4*)sWf;
#pragma unroll
    for (int i = 0; i < 8; i++) S4[i * 256 + t] = W4[i * 256 + t];
    if (statsOut) sstat[t] = 0.f;
    __syncthreads();

    f32x4 acc[8];
#pragma unroll
    for (int i = 0; i < 8; i++) acc[i] = (f32x4)(0.f);

#pragma unroll
    for (int kt = 0; kt < 4; kt++) {
#pragma unroll
        for (int nt = 0; nt < 8; nt++) {
            bf16x8 bf = *(const bf16x8*)(sWf + ((kt * 8 + nt) * 64 + lane) * 8);
            acc[nt] = __builtin_amdgcn_mfma_f32_16x16x32_bf16(afr[kt], bf, acc[nt], 0, 0, 0);
        }
    }

    __syncthreads();   // all waves done with half 1 before overwrite
#pragma unroll
    for (int i = 0; i < 8; i++) S4[i * 256 + t] = W4[2048 + i * 256 + t];
    __syncthreads();

#pragma unroll
    for (int kt = 4; kt < 8; kt++) {
#pragma unroll
        for (int nt = 0; nt < 8; nt++) {
            bf16x8 bf = *(const bf16x8*)(sWf + (((kt - 4) * 8 + nt) * 64 + lane) * 8);
            acc[nt] = __builtin_amdgcn_mfma_f32_16x16x32_bf16(afr[kt], bf, acc[nt], 0, 0, 0);
        }
    }

    const bool do16 = (out16 != nullptr);
#pragma unroll
    for (int nt = 0; nt < 8; nt++) {
        int cidx = nt * 16 + m;
        float bv = bias[cidx];
        float s = 0.f, q = 0.f;
#pragma unroll
        for (int reg = 0; reg < 4; reg++) {
            int r = wrow0 + quad * 4 + reg;
            float v = acc[nt][reg] + bv;
            if (r < N_NODES) {
                if (do16) out16[(size_t)r * D + cidx] = f2bf(v);
                else      outf[(size_t)r * D + cidx] = v;
                s += v; q += v * v;
            }
        }
        if (statsOut) {
            s += __shfl_xor(s, 16); s += __shfl_xor(s, 32);
            q += __shfl_xor(q, 16); q += __shfl_xor(q, 32);
            if (quad == 0) {
                atomicAdd(&sstat[cidx], s);
                atomicAdd(&sstat[128 + cidx], q);
            }
        }
    }
    if (statsOut) {
        __syncthreads();
        atomicAdd(&statsOut[(blockIdx.x & (NREP - 1)) * 256 + t], sstat[t]);
    }
}

// ---------------- launch ----------------

extern "C" void kernel_launch(void* const* d_in, const int* in_sizes, int n_in,
                              void* d_out, int out_size, void* d_ws, size_t ws_size,
                              hipStream_t stream) {
    const float* x   = (const float*)d_in[0];
    const int* src   = (const int*)d_in[1];
    const int* dst   = (const int*)d_in[2];
    const float* Ws0 = (const float*)d_in[3];
    const float* Wn0 = (const float*)d_in[4];
    const float* b0  = (const float*)d_in[5];
    const float* Ws1 = (const float*)d_in[6];
    const float* Wn1 = (const float*)d_in[7];
    const float* b1  = (const float*)d_in[8];
    const float* Ws2 = (const float*)d_in[9];
    const float* Wn2 = (const float*)d_in[10];
    const float* b2  = (const float*)d_in[11];
    const float* g0  = (const float*)d_in[12];
    const float* be0 = (const float*)d_in[13];
    const float* g1  = (const float*)d_in[14];
    const float* be1 = (const float*)d_in[15];

    char* base = (char*)d_ws;
    size_t NND = (size_t)N_NODES * D;
    unsigned short* X16    = (unsigned short*)base;                 // 12.8 MB
    unsigned short* H16    = (unsigned short*)(base + NND * 2);     // 12.8 MB
    unsigned short* mean16 = (unsigned short*)(base + 2 * NND * 2); // 12.8 MB
    char* p = base + 6 * NND;
    unsigned short* Wf = (unsigned short*)p;  p += 3 * 32768 * 2;                  // 192 KB
    int* hist          = (int*)p;             p += (size_t)S1_BLOCKS * NBUCK * 4;  // 400 KB
    int* bucketTotal   = (int*)p;             p += 1568;
    int* bucketStart   = (int*)p;             p += 1600;
    unsigned int* rec  = (unsigned int*)p;    p += (size_t)N_EDGES * 4;            // 3.2 MB
    unsigned short* csr = (unsigned short*)p; p += (size_t)N_EDGES * 2;            // 1.6 MB
    int* degi    = (int*)p;                   p += N_NODES * 4;
    int* offsets = (int*)p;                   p += N_NODES * 4;
    float* inv_deg = (float*)p;               p += N_NODES * 4;
    float* stats   = (float*)p;               p += 2 * NREP * 256 * 4;  // replicated
    float* stats0 = stats, *stats1 = stats + NREP * 256;

    // prep: feature convert + edge histogram + weight pack + zero stats
    fused_prep<<<CVT_BLOCKS + S1_BLOCKS + PACK_BLOCKS, 256, 0, stream>>>(
        x, X16, dst, hist, Ws0, Wn0, Ws1, Wn1, Ws2, Wn2, Wf, stats);
    // CSR build: 3 kernels (s2b folded into s3 as redundant per-block scan)
    s2a<<<NBUCK, 256, 0, stream>>>(hist, bucketTotal);
    s3_scatter<<<S1_BLOCKS, 256, 0, stream>>>(src, dst, hist, bucketTotal, bucketStart, rec);
    s4_build<<<NBUCK, 256, 0, stream>>>(rec, bucketStart, csr, degi, offsets, inv_deg);

    const int AGG_B = (N_NODES + 15) / 16;   // 3125
    const int GEMM_B = (N_NODES + 63) / 64;  // 782

    // Layer 0: X16 -> H16 raw + stats0
    aggregate16<<<AGG_B, 256, 0, stream>>>(X16, csr, offsets, degi, inv_deg, mean16);
    sage_gemm<<<GEMM_B, 256, 0, stream>>>(X16, mean16, Wf, b0, H16, nullptr, stats0);

    // Layer 1: H16 <- relu(bn0(H16)); -> X16 raw + stats1
    bn_relu_apply<<<BN_BLOCKS, 256, 0, stream>>>(H16, stats0, g0, be0);
    aggregate16<<<AGG_B, 256, 0, stream>>>(H16, csr, offsets, degi, inv_deg, mean16);
    sage_gemm<<<GEMM_B, 256, 0, stream>>>(H16, mean16, Wf + 32768, b1, X16, nullptr, stats1);

    // Layer 2: X16 <- relu(bn1(X16)); -> d_out fp32
    bn_relu_apply<<<BN_BLOCKS, 256, 0, stream>>>(X16, stats1, g1, be1);
    aggregate16<<<AGG_B, 256, 0, stream>>>(X16, csr, offsets, degi, inv_deg, mean16);
    sage_gemm<<<GEMM_B, 256, 0, stream>>>(X16, mean16, Wf + 65536, b2, nullptr,
                                          (float*)d_out, nullptr);
}

// Round 7
// 278.030 us; speedup vs baseline: 1.0604x; 1.0106x over previous
//
#include <hip/hip_runtime.h>

#define N_NODES 50000
#define N_EDGES 800000
#define D 128
#define BN_EPS 1e-5f

#define NBUCK 391        // ceil(N_NODES / 128)
#define BSHIFT 7         // 128 nodes per bucket
#define S1_BLOCKS 256
#define EPB 3125         // edges per histogram/scatter block (256*3125 == 800000)
#define CVT_BLOCKS 6250  // N_NODES*D/4 / 256
#define PACK_BLOCKS 384  // 3*32768 / 256
#define NREP 16          // stats replica count (atomic-contention spread)
#define NSLICE 8         // src-slice bins for L2-locality sort (50000>>13 -> 0..6)
#define SSHIFT 13        // 8192 nodes/slice = 2 MB of bf16 rows (fits per-XCD L2)
#define BN_BLOCKS 512

typedef __attribute__((ext_vector_type(8))) short bf16x8;
typedef __attribute__((ext_vector_type(4))) float f32x4;
typedef __attribute__((ext_vector_type(2))) float f32x2;

// fp32 -> bf16 (RNE)
__device__ inline unsigned short f2bf(float f) {
    unsigned int u = __float_as_uint(f);
    u = (u + 0x7FFF + ((u >> 16) & 1)) >> 16;
    return (unsigned short)u;
}

__device__ inline float bf2f(unsigned short b) {
    return __uint_as_float(((unsigned)b) << 16);
}

// packed-pair accumulate: 2 extracts + 1 (pk_)add per bf16 pair
__device__ __forceinline__ void acc_plain(f32x2* a, uint4 v) {
    unsigned w[4] = {v.x, v.y, v.z, v.w};
#pragma unroll
    for (int p = 0; p < 4; p++) {
        f32x2 f;
        f.x = __uint_as_float(w[p] << 16);          // even col
        f.y = __uint_as_float(w[p] & 0xffff0000u);  // odd col
        a[p] += f;
    }
}

// ---------------- fused prep: convert_x | edge histogram | pack_w (+zero) ----------

__global__ void fused_prep(const float* __restrict__ x, unsigned short* __restrict__ x16,
                           const int* __restrict__ dst, int* __restrict__ hist,
                           const float* __restrict__ Ws0, const float* __restrict__ Wn0,
                           const float* __restrict__ Ws1, const float* __restrict__ Wn1,
                           const float* __restrict__ Ws2, const float* __restrict__ Wn2,
                           unsigned short* __restrict__ Wf, float* __restrict__ statsg) {
    __shared__ int lh[NBUCK];
    const int bid = blockIdx.x, t = threadIdx.x;

    if (bid < CVT_BLOCKS) {
        int idx = bid * 256 + t;
        float4 v = ((const float4*)x)[idx];
        ushort4 o;
        o.x = f2bf(v.x); o.y = f2bf(v.y); o.z = f2bf(v.z); o.w = f2bf(v.w);
        ((ushort4*)x16)[idx] = o;
    } else if (bid < CVT_BLOCKS + S1_BLOCKS) {
        int blk = bid - CVT_BLOCKS;
        for (int i = t; i < NBUCK; i += 256) lh[i] = 0;
        __syncthreads();
        int e0 = blk * EPB;
        for (int i = 0; i < 13; i++) {
            int k = t + i * 256;
            if (k < EPB) atomicAdd(&lh[dst[e0 + k] >> BSHIFT], 1);
        }
        __syncthreads();
        for (int i = t; i < NBUCK; i += 256) hist[blk * NBUCK + i] = lh[i];
    } else {
        if (bid == CVT_BLOCKS + S1_BLOCKS) {   // zero BN stats: 2 layers x NREP x 256
            for (int i = t; i < 2 * NREP * 256; i += 256) statsg[i] = 0.f;
        }
        // pack weights into MFMA B-fragment order:
        // Wf[layer][kt(8)][nt(8)][lane(64)][j(8)], lane l holds
        // B[kt*32 + 8*(l>>4) + j][nt*16 + (l&15)].
        int idx = (bid - (CVT_BLOCKS + S1_BLOCKS)) * 256 + t;
        if (idx < 3 * 32768) {
            int layer = idx >> 15;
            int rem = idx & 32767;
            int kt = rem >> 12;
            int nt = (rem >> 9) & 7;
            int lane = (rem >> 3) & 63;
            int j = rem & 7;
            int k = kt * 32 + (lane >> 4) * 8 + j;
            int n = nt * 16 + (lane & 15);
            const float* Wsrc;
            if (layer == 0) Wsrc = (k < 128) ? Ws0 : Wn0;
            else if (layer == 1) Wsrc = (k < 128) ? Ws1 : Wn1;
            else Wsrc = (k < 128) ? Ws2 : Wn2;
            Wf[idx] = f2bf(Wsrc[(k & 127) * D + n]);
        }
    }
}

// ---------------- S2a: per-bucket exclusive prefix over blocks ----------------
// Separate kernels on purpose: round-7's grid-barrier merge (sort_all) ran 97 us
// vs ~35 us for this pipeline — barrier serialization at 1 block/CU.

__global__ void s2a(int* __restrict__ hist, int* __restrict__ bucketTotal) {
    __shared__ int s[S1_BLOCKS];
    int b = blockIdx.x, t = threadIdx.x;
    int v = hist[t * NBUCK + b];
    s[t] = v;
    __syncthreads();
    for (int off = 1; off < S1_BLOCKS; off <<= 1) {
        int x = (t >= off) ? s[t - off] : 0;
        __syncthreads();
        s[t] += x;
        __syncthreads();
    }
    hist[t * NBUCK + b] = s[t] - v;
    if (t == S1_BLOCKS - 1) bucketTotal[b] = s[t];
}

// ---------------- S3: scatter packed records, bucket-grouped ----------------
// Each block redundantly scans the 391 bucket totals in LDS (cheap, parallel —
// removes the s2b dispatch); block 0 publishes bucketStart for s4_build.

__global__ void s3_scatter(const int* __restrict__ src, const int* __restrict__ dst,
                           const int* __restrict__ hist, const int* __restrict__ bucketTotal,
                           int* __restrict__ bucketStart, unsigned int* __restrict__ rec) {
    __shared__ int sc[512];
    __shared__ int base[NBUCK];
    int blk = blockIdx.x, t = threadIdx.x;
    int i1 = t + 256;
    int v0 = (t < NBUCK) ? bucketTotal[t] : 0;
    int v1 = (i1 < NBUCK) ? bucketTotal[i1] : 0;
    sc[t] = v0; sc[i1] = v1;
    __syncthreads();
    for (int off = 1; off < 512; off <<= 1) {
        int x0 = (t >= off) ? sc[t - off] : 0;
        int x1 = (i1 >= off) ? sc[i1 - off] : 0;
        __syncthreads();
        sc[t] += x0; sc[i1] += x1;
        __syncthreads();
    }
    if (t < NBUCK)  base[t]  = (sc[t] - v0)  + hist[blk * NBUCK + t];
    if (i1 < NBUCK) base[i1] = (sc[i1] - v1) + hist[blk * NBUCK + i1];
    if (blk == 0) {
        if (t < NBUCK)  bucketStart[t]  = sc[t] - v0;
        if (i1 < NBUCK) bucketStart[i1] = sc[i1] - v1;
        if (t == 0) bucketStart[NBUCK] = N_EDGES;
    }
    __syncthreads();
    int e0 = blk * EPB;
    for (int i = 0; i < 13; i++) {
        int k = t + i * 256;
        if (k < EPB) {
            int e = e0 + k;
            int d = dst[e];
            int p = atomicAdd(&base[d >> BSHIFT], 1);
            rec[p] = ((unsigned)(d & 127) << 16) | (unsigned)src[e];
        }
    }
}

// ---------------- S4: per-bucket counting sort -> CSR + degrees ----------------
// Round-11: sort key extended to (dst&127, src>>13) so each neighbor list is
// grouped by 2 MB source slice. All aggregate16 blocks then sweep slices in
// loose lockstep -> gather working set becomes L2-resident per XCD.

__global__ void s4_build(const unsigned int* __restrict__ rec, const int* __restrict__ bucketStart,
                         unsigned short* __restrict__ csr, int* __restrict__ degi,
                         int* __restrict__ offsets, float* __restrict__ inv_deg) {
    __shared__ int cnt[128 * NSLICE];
    __shared__ int exc[128 * NSLICE];
    __shared__ int lcur[128 * NSLICE];
    __shared__ int ls[256];
    int b = blockIdx.x, t = threadIdx.x;
    int start = bucketStart[b], end = bucketStart[b + 1];

    for (int i = t; i < 128 * NSLICE; i += 256) cnt[i] = 0;
    __syncthreads();
    for (int e = start + t; e < end; e += 256) {
        unsigned r = rec[e];
        int key = ((r >> 16) << 3) | ((r & 0xFFFFu) >> SSHIFT);
        atomicAdd(&cnt[key], 1);
    }
    __syncthreads();

    // 1024-bin exclusive scan: 4 bins/thread, block scan over partials
    int c0 = cnt[4 * t], c1 = cnt[4 * t + 1], c2 = cnt[4 * t + 2], c3 = cnt[4 * t + 3];
    int sum4 = c0 + c1 + c2 + c3;
    ls[t] = sum4;
    __syncthreads();
    for (int off = 1; off < 256; off <<= 1) {
        int x = (t >= off) ? ls[t - off] : 0;
        __syncthreads();
        ls[t] += x;
        __syncthreads();
    }
    int base = ls[t] - sum4;
    exc[4 * t]     = base;
    exc[4 * t + 1] = base + c0;
    exc[4 * t + 2] = base + c0 + c1;
    exc[4 * t + 3] = base + c0 + c1 + c2;
    lcur[4 * t]     = start + base;
    lcur[4 * t + 1] = start + base + c0;
    lcur[4 * t + 2] = start + base + c0 + c1;
    lcur[4 * t + 3] = start + base + c0 + c1 + c2;
    __syncthreads();

    if (t < 128) {
        int node = (b << BSHIFT) + t;
        int e0 = exc[8 * t];
        int e1 = (t == 127) ? (end - start) : exc[8 * t + 8];
        int v = e1 - e0;
        if (node < N_NODES) {
            degi[node] = v;
            offsets[node] = start + e0;
            inv_deg[node] = 1.0f / (float)max(v, 1);
        }
    }
    __syncthreads();
    for (int e = start + t; e < end; e += 256) {
        unsigned r = rec[e];
        int key = ((r >> 16) << 3) | ((r & 0xFFFFu) >> SSHIFT);
        int p = atomicAdd(&lcur[key], 1);
        csr[p] = (unsigned short)(r & 0xFFFFu);
    }
}

// ---------------- BN+ReLU applied once per node (round-11) ----------------
// Replaces the per-edge BN in aggregate16 (16x amplified VALU + per-thread
// stats refold = ~400 MB of redundant L2 loads) and the self-fragment BN in
// sage_gemm. In-place on the bf16 activation buffer.

__global__ void bn_relu_apply(unsigned short* __restrict__ h,
                              const float* __restrict__ stats,
                              const float* __restrict__ gamma, const float* __restrict__ beta) {
    __shared__ float sc[128], sh[128];
    int t = threadIdx.x;
    if (t < 128) {
        const float invN = 1.0f / (float)N_NODES;
        float s = 0.f, q = 0.f;
#pragma unroll
        for (int r = 0; r < NREP; r++) {
            s += stats[r * 256 + t];
            q += stats[r * 256 + 128 + t];
        }
        float m = s * invN;
        float var = q * invN - m * m;
        float scv = rsqrtf(var + BN_EPS) * gamma[t];
        sc[t] = scv;
        sh[t] = beta[t] - m * scv;
    }
    __syncthreads();
    const int total = N_NODES * D / 8;  // 800000 uint4
    for (int idx = blockIdx.x * 256 + t; idx < total; idx += BN_BLOCKS * 256) {
        uint4 v = ((const uint4*)h)[idx];
        int col0 = (idx & 15) * 8;
        unsigned w[4] = {v.x, v.y, v.z, v.w};
        unsigned ow[4];
#pragma unroll
        for (int p = 0; p < 4; p++) {
            float lo = __uint_as_float(w[p] << 16);
            float hi = __uint_as_float(w[p] & 0xffff0000u);
            float rlo = fmaxf(lo * sc[col0 + 2 * p]     + sh[col0 + 2 * p],     0.f);
            float rhi = fmaxf(hi * sc[col0 + 2 * p + 1] + sh[col0 + 2 * p + 1], 0.f);
            ow[p] = ((unsigned)f2bf(rhi) << 16) | f2bf(rlo);
        }
        uint4 o;
        o.x = ow[0]; o.y = ow[1]; o.z = ow[2]; o.w = ow[3];
        ((uint4*)h)[idx] = o;
    }
}

// ---------------- mean aggregation (round-16: batched csr + register broadcast) ---
// Rounds 4/5/6 falsified divergence & buffering theories; the remaining serial
// structure is the per-edge TWO-hop chain csr[beg+k] -> row gather (~2x L2/L3
// latency per pipeline step, and 16 lanes redundantly load the same csr entry).
// Fix: each 16-lane group bulk-loads up to 48 neighbor indices in 3 coalesced
// u16 loads (covers Poisson(16) to ~6 sigma); edge k's row comes from
// __shfl(cbX, k&15, 16) — register broadcast, no memory hop. Row gathers are
// then address-independent of in-flight loads; the 4-deep pipeline issues them
// back-to-back at L(row) only. Rare n>48 tail uses direct csr loads.

#define GROW(r) (*(const uint4*)(hb + ((size_t)(r) << 7)))
#define ROWIDX(k) __shfl((int)((k) < 16 ? cb0 : ((k) < 32 ? cb1 : cb2)), (k) & 15, 16)

__global__ void aggregate16(const unsigned short* __restrict__ h16,
                            const unsigned short* __restrict__ csr, const int* __restrict__ offsets,
                            const int* __restrict__ degi, const float* __restrict__ inv_deg,
                            unsigned short* __restrict__ mean16) {
    int t = threadIdx.x;
    int node = blockIdx.x * 16 + (t >> 4);   // grid*16 == N_NODES exactly
    int c = t & 15;
    const unsigned short* hb = h16 + c * 8;
    int beg = offsets[node], n = degi[node];

    // batch-load up to 48 neighbor indices (lane c holds entries c, 16+c, 32+c)
    int ci = beg + c;
    int cmax = N_EDGES - 1;
    unsigned cb0 = csr[min(ci, cmax)];
    unsigned cb1 = csr[min(ci + 16, cmax)];
    unsigned cb2 = csr[min(ci + 32, cmax)];

    f32x2 a[4];
#pragma unroll
    for (int j = 0; j < 4; j++) a[j] = (f32x2)(0.f);

    int nfast = n < 48 ? n : 48;
    int i = 0;
    if (nfast >= 4) {
        uint4 v0 = GROW(ROWIDX(0)), v1 = GROW(ROWIDX(1));
        uint4 v2 = GROW(ROWIDX(2)), v3 = GROW(ROWIDX(3));
        for (i = 4; i + 3 < nfast; i += 4) {
            int r0 = ROWIDX(i), r1 = ROWIDX(i + 1), r2 = ROWIDX(i + 2), r3 = ROWIDX(i + 3);
            uint4 w0 = GROW(r0), w1 = GROW(r1), w2 = GROW(r2), w3 = GROW(r3);
            acc_plain(a, v0); acc_plain(a, v1); acc_plain(a, v2); acc_plain(a, v3);
            v0 = w0; v1 = w1; v2 = w2; v3 = w3;
        }
        acc_plain(a, v0); acc_plain(a, v1); acc_plain(a, v2); acc_plain(a, v3);
    }
    for (; i < nfast; i++) { uint4 v = GROW(ROWIDX(i)); acc_plain(a, v); }
    for (; i < n; i++) { int r = csr[beg + i]; uint4 v = GROW(r); acc_plain(a, v); }

    float w = inv_deg[node];
    uint4 o;
    o.x = ((unsigned)f2bf(a[0].y * w) << 16) | f2bf(a[0].x * w);
    o.y = ((unsigned)f2bf(a[1].y * w) << 16) | f2bf(a[1].x * w);
    o.z = ((unsigned)f2bf(a[2].y * w) << 16) | f2bf(a[2].x * w);
    o.w = ((unsigned)f2bf(a[3].y * w) << 16) | f2bf(a[3].x * w);
    *(uint4*)(mean16 + (size_t)node * D + c * 8) = o;
}

// ---------------- MFMA SAGE GEMM + fused BN col-stats ----------------
// Round-10 restructure: Wf staged in LDS 32KB at a time; B-frags via
// ds_read_b128; all 8 A-frags register-prefetched. Inputs are post-BN
// (round-11) so no self-fragment BN here. Stats scattered across NREP
// replica slots.
// C/D layout (m89-verified): col = lane&15, row = (lane>>4)*4 + reg.

__global__ __launch_bounds__(256, 4) void sage_gemm(
    const unsigned short* __restrict__ h16, const unsigned short* __restrict__ mean16,
    const unsigned short* __restrict__ Wf, const float* __restrict__ bias,
    unsigned short* __restrict__ out16, float* __restrict__ outf,
    float* __restrict__ statsOut) {
    __shared__ unsigned short sWf[16384];   // 32 KB: one K-half (4 kt x 8 nt x 64 x 8)
    __shared__ float sstat[256];
    const int t = threadIdx.x;
    const int lane = t & 63;
    const int m = lane & 15;
    const int quad = lane >> 4;
    const int wrow0 = blockIdx.x * 64 + (t >> 6) * 16;

    int arow = wrow0 + m;
    if (arow >= N_NODES) arow = N_NODES - 1;

    // prefetch all 8 A-fragments (4 self + 4 mean) into registers
    bf16x8 afr[8];
#pragma unroll
    for (int kt = 0; kt < 4; kt++)
        afr[kt] = *(const bf16x8*)(h16 + (size_t)arow * D + kt * 32 + quad * 8);
#pragma unroll
    for (int kt = 0; kt < 4; kt++)
        afr[4 + kt] = *(const bf16x8*)(mean16 + (size_t)arow * D + kt * 32 + quad * 8);

    // stage first weight half (kt 0-3)
    const uint4* W4 = (const uint4*)Wf;
    uint4* S4 = (uint4*)sWf;
#pragma unroll
    for (int i = 0; i < 8; i++) S4[i * 256 + t] = W4[i * 256 + t];
    if (statsOut) sstat[t] = 0.f;
    __syncthreads();

    f32x4 acc[8];
#pragma unroll
    for (int i = 0; i < 8; i++) acc[i] = (f32x4)(0.f);

#pragma unroll
    for (int kt = 0; kt < 4; kt++) {
#pragma unroll
        for (int nt = 0; nt < 8; nt++) {
            bf16x8 bf = *(const bf16x8*)(sWf + ((kt * 8 + nt) * 64 + lane) * 8);
            acc[nt] = __builtin_amdgcn_mfma_f32_16x16x32_bf16(afr[kt], bf, acc[nt], 0, 0, 0);
        }
    }

    __syncthreads();   // all waves done with half 1 before overwrite
#pragma unroll
    for (int i = 0; i < 8; i++) S4[i * 256 + t] = W4[2048 + i * 256 + t];
    __syncthreads();

#pragma unroll
    for (int kt = 4; kt < 8; kt++) {
#pragma unroll
        for (int nt = 0; nt < 8; nt++) {
            bf16x8 bf = *(const bf16x8*)(sWf + (((kt - 4) * 8 + nt) * 64 + lane) * 8);
            acc[nt] = __builtin_amdgcn_mfma_f32_16x16x32_bf16(afr[kt], bf, acc[nt], 0, 0, 0);
        }
    }

    const bool do16 = (out16 != nullptr);
#pragma unroll
    for (int nt = 0; nt < 8; nt++) {
        int cidx = nt * 16 + m;
        float bv = bias[cidx];
        float s = 0.f, q = 0.f;
#pragma unroll
        for (int reg = 0; reg < 4; reg++) {
            int r = wrow0 + quad * 4 + reg;
            float v = acc[nt][reg] + bv;
            if (r < N_NODES) {
                if (do16) out16[(size_t)r * D + cidx] = f2bf(v);
                else      outf[(size_t)r * D + cidx] = v;
                s += v; q += v * v;
            }
        }
        if (statsOut) {
            s += __shfl_xor(s, 16); s += __shfl_xor(s, 32);
            q += __shfl_xor(q, 16); q += __shfl_xor(q, 32);
            if (quad == 0) {
                atomicAdd(&sstat[cidx], s);
                atomicAdd(&sstat[128 + cidx], q);
            }
        }
    }
    if (statsOut) {
        __syncthreads();
        atomicAdd(&statsOut[(blockIdx.x & (NREP - 1)) * 256 + t], sstat[t]);
    }
}

// ---------------- launch ----------------

extern "C" void kernel_launch(void* const* d_in, const int* in_sizes, int n_in,
                              void* d_out, int out_size, void* d_ws, size_t ws_size,
                              hipStream_t stream) {
    const float* x   = (const float*)d_in[0];
    const int* src   = (const int*)d_in[1];
    const int* dst   = (const int*)d_in[2];
    const float* Ws0 = (const float*)d_in[3];
    const float* Wn0 = (const float*)d_in[4];
    const float* b0  = (const float*)d_in[5];
    const float* Ws1 = (const float*)d_in[6];
    const float* Wn1 = (const float*)d_in[7];
    const float* b1  = (const float*)d_in[8];
    const float* Ws2 = (const float*)d_in[9];
    const float* Wn2 = (const float*)d_in[10];
    const float* b2  = (const float*)d_in[11];
    const float* g0  = (const float*)d_in[12];
    const float* be0 = (const float*)d_in[13];
    const float* g1  = (const float*)d_in[14];
    const float* be1 = (const float*)d_in[15];

    char* base = (char*)d_ws;
    size_t NND = (size_t)N_NODES * D;
    unsigned short* X16    = (unsigned short*)base;                 // 12.8 MB
    unsigned short* H16    = (unsigned short*)(base + NND * 2);     // 12.8 MB
    unsigned short* mean16 = (unsigned short*)(base + 2 * NND * 2); // 12.8 MB
    char* p = base + 6 * NND;
    unsigned short* Wf = (unsigned short*)p;  p += 3 * 32768 * 2;                  // 192 KB
    int* hist          = (int*)p;             p += (size_t)S1_BLOCKS * NBUCK * 4;  // 400 KB
    int* bucketTotal   = (int*)p;             p += 1568;
    int* bucketStart   = (int*)p;             p += 1600;
    unsigned int* rec  = (unsigned int*)p;    p += (size_t)N_EDGES * 4;            // 3.2 MB
    unsigned short* csr = (unsigned short*)p; p += (size_t)N_EDGES * 2;            // 1.6 MB
    int* degi    = (int*)p;                   p += N_NODES * 4;
    int* offsets = (int*)p;                   p += N_NODES * 4;
    float* inv_deg = (float*)p;               p += N_NODES * 4;
    float* stats   = (float*)p;               p += 2 * NREP * 256 * 4;  // replicated
    float* stats0 = stats, *stats1 = stats + NREP * 256;

    // prep: feature convert + edge histogram + weight pack + zero stats
    fused_prep<<<CVT_BLOCKS + S1_BLOCKS + PACK_BLOCKS, 256, 0, stream>>>(
        x, X16, dst, hist, Ws0, Wn0, Ws1, Wn1, Ws2, Wn2, Wf, stats);
    // CSR build: 3 kernels (s2b folded into s3 as redundant per-block scan)
    s2a<<<NBUCK, 256, 0, stream>>>(hist, bucketTotal);
    s3_scatter<<<S1_BLOCKS, 256, 0, stream>>>(src, dst, hist, bucketTotal, bucketStart, rec);
    s4_build<<<NBUCK, 256, 0, stream>>>(rec, bucketStart, csr, degi, offsets, inv_deg);

    const int AGG_B = (N_NODES + 15) / 16;   // 3125
    const int GEMM_B = (N_NODES + 63) / 64;  // 782

    // Layer 0: X16 -> H16 raw + stats0
    aggregate16<<<AGG_B, 256, 0, stream>>>(X16, csr, offsets, degi, inv_deg, mean16);
    sage_gemm<<<GEMM_B, 256, 0, stream>>>(X16, mean16, Wf, b0, H16, nullptr, stats0);

    // Layer 1: H16 <- relu(bn0(H16)); -> X16 raw + stats1
    bn_relu_apply<<<BN_BLOCKS, 256, 0, stream>>>(H16, stats0, g0, be0);
    aggregate16<<<AGG_B, 256, 0, stream>>>(H16, csr, offsets, degi, inv_deg, mean16);
    sage_gemm<<<GEMM_B, 256, 0, stream>>>(H16, mean16, Wf + 32768, b1, X16, nullptr, stats1);

    // Layer 2: X16 <- relu(bn1(X16)); -> d_out fp32
    bn_relu_apply<<<BN_BLOCKS, 256, 0, stream>>>(X16, stats1, g1, be1);
    aggregate16<<<AGG_B, 256, 0, stream>>>(X16, csr, offsets, degi, inv_deg, mean16);
    sage_gemm<<<GEMM_B, 256, 0, stream>>>(X16, mean16, Wf + 65536, b2, nullptr,
                                          (float*)d_out, nullptr);
}